// Round 5
// baseline (300.934 us; speedup 1.0000x reference)
//
#include <hip/hip_runtime.h>
#include <math.h>

#define BB 16
#define TT 4096
#define DD 1024
#define HH 32
#define TCHUNK 64
#define NCHUNK (TT / TCHUNK)   // 64

static constexpr float kEPS = 1e-6f;

typedef float f32x4 __attribute__((ext_vector_type(4)));

// ---------------- Kernel 1: masked partial sums over T ----------------
// grid: (NCHUNK, B), 256 threads; thread owns 4 consecutive d (256*4 = D).
// Normal loads: K1 is what seeds L3 with Z for K3's harvest.
__global__ __launch_bounds__(256) void reduce_kernel(
    const float* __restrict__ zr, const float* __restrict__ zi,
    const float* __restrict__ mask,
    float* __restrict__ partR, float* __restrict__ partI,
    float* __restrict__ cntP) {
  const int c = blockIdx.x;
  const int b = blockIdx.y;
  const int tid = threadIdx.x;
  const int d4 = tid * 4;

  f32x4 accR = (f32x4)(0.f);
  f32x4 accI = (f32x4)(0.f);
  float msum = 0.f;

  const size_t base = ((size_t)b * TT + (size_t)c * TCHUNK) * DD + d4;
  const float* zrp = zr + base;
  const float* zip = zi + base;
  const float* mp = mask + (size_t)b * TT + (size_t)c * TCHUNK;

  #pragma unroll 8
  for (int t = 0; t < TCHUNK; ++t) {
    const float m = mp[t];
    msum += m;
    f32x4 r  = *(const f32x4*)(zrp + (size_t)t * DD);
    f32x4 im = *(const f32x4*)(zip + (size_t)t * DD);
    accR += r * m;
    accI += im * m;
  }

  const size_t po = ((size_t)c * BB + b) * DD + d4;
  *(f32x4*)(partR + po) = accR;
  *(f32x4*)(partI + po) = accI;
  if (tid == 0) cntP[c * BB + b] = msum;
}

// ---------------- Kernel 2: reduce partials + per-(b,d) MLP ----------------
__global__ __launch_bounds__(256) void mlp_kernel(
    const float* __restrict__ partR, const float* __restrict__ partI,
    const float* __restrict__ cntP,
    const float* __restrict__ W1m, const float* __restrict__ b1m,
    const float* __restrict__ W2m, const float* __restrict__ b2m,
    const float* __restrict__ W1p, const float* __restrict__ b1p,
    const float* __restrict__ W2p, const float* __restrict__ b2p,
    const float* __restrict__ mag_scale,
    float* __restrict__ anR, float* __restrict__ anI) {
  const int i = blockIdx.x * blockDim.x + threadIdx.x;
  const int b = i >> 10;   // D = 1024
  const int d = i & (DD - 1);

  __shared__ float cntS;
  if (threadIdx.x == 0) {
    float s = 0.f;
    for (int c = 0; c < NCHUNK; ++c) s += cntP[c * BB + b];
    cntS = s;
  }
  __syncthreads();

  float sR = 0.f, sI = 0.f;
  for (int c = 0; c < NCHUNK; ++c) {
    const size_t po = ((size_t)c * BB + b) * DD + d;
    sR += partR[po];
    sI += partI[po];
  }

  const float count = fmaxf(cntS, 1.0f);
  const float Ar = sR / count;
  const float Ai = sI / count;
  const float mag = sqrtf(Ar * Ar + Ai * Ai);
  const float log_mag = logf(mag + kEPS);
  const float inv_me = 1.0f / (mag + kEPS);
  const float pr = Ar * inv_me;
  const float pi = Ai * inv_me;

  float md = b2m[0];
  #pragma unroll
  for (int j = 0; j < HH; ++j) {
    float h = log_mag * W1m[j] + b1m[j];
    h = 0.5f * h * (1.0f + erff(h * 0.70710678118654752440f));
    md += h * W2m[j];
  }
  const float lmo = log_mag + mag_scale[0] * md;

  float pv0 = b2p[0];
  float pv1 = b2p[1];
  #pragma unroll
  for (int j = 0; j < HH; ++j) {
    float hp = pr * W1p[2 * j] + pi * W1p[2 * j + 1] + b1p[j];
    hp = 0.5f * hp * (1.0f + erff(hp * 0.70710678118654752440f));
    pv0 += hp * W2p[j];       // W2p[0][j]
    pv1 += hp * W2p[HH + j];  // W2p[1][j]
  }
  const float nrm = fmaxf(sqrtf(pv0 * pv0 + pv1 * pv1), 1e-12f);
  const float r_out = expf(lmo);
  anR[i] = r_out * pv0 / nrm;
  anI[i] = r_out * pv1 / nrm;
}

// ---------------- Kernel 3: broadcast add + write both planes ----------------
// Same layout as K1, t walked BACKWARD. Split policy:
//   t in [32,63]: expected L3-resident (K1's MRU tail)  -> NORMAL loads (hit path)
//   t in [0,31]:  expected HBM miss                     -> NT loads (don't evict
//                 the not-yet-consumed resident tails of other chunks)
// Stores always NT (no write-allocate pollution of L3).
__global__ __launch_bounds__(256) void add_kernel(
    const float* __restrict__ zr, const float* __restrict__ zi,
    const float* __restrict__ anR, const float* __restrict__ anI,
    float* __restrict__ out) {
  const int c = blockIdx.x;
  const int b = blockIdx.y;
  const int tid = threadIdx.x;
  const int d4 = tid * 4;

  const int o = b * DD + d4;
  const f32x4 ar4 = *(const f32x4*)(anR + o);
  const f32x4 ai4 = *(const f32x4*)(anI + o);

  const size_t base = ((size_t)b * TT + (size_t)c * TCHUNK) * DD + d4;
  const float* zrp = zr + base;
  const float* zip = zi + base;
  float* out0 = out + base;
  float* out1 = out + (size_t)BB * TT * DD + base;

  // expected-hit half: normal loads
  #pragma unroll 8
  for (int t = TCHUNK - 1; t >= TCHUNK / 2; --t) {
    const size_t ro = (size_t)t * DD;
    f32x4 r  = *(const f32x4*)(zrp + ro);
    f32x4 im = *(const f32x4*)(zip + ro);
    r += ar4;
    im += ai4;
    __builtin_nontemporal_store(r, (f32x4*)(out0 + ro));
    __builtin_nontemporal_store(im, (f32x4*)(out1 + ro));
  }
  // expected-miss half: nt loads
  #pragma unroll 8
  for (int t = TCHUNK / 2 - 1; t >= 0; --t) {
    const size_t ro = (size_t)t * DD;
    f32x4 r  = __builtin_nontemporal_load((const f32x4*)(zrp + ro));
    f32x4 im = __builtin_nontemporal_load((const f32x4*)(zip + ro));
    r += ar4;
    im += ai4;
    __builtin_nontemporal_store(r, (f32x4*)(out0 + ro));
    __builtin_nontemporal_store(im, (f32x4*)(out1 + ro));
  }
}

extern "C" void kernel_launch(void* const* d_in, const int* in_sizes, int n_in,
                              void* d_out, int out_size, void* d_ws, size_t ws_size,
                              hipStream_t stream) {
  const float* zr = (const float*)d_in[0];
  const float* zi = (const float*)d_in[1];
  const float* mask = (const float*)d_in[2];
  const float* W1m = (const float*)d_in[3];
  const float* b1m = (const float*)d_in[4];
  const float* W2m = (const float*)d_in[5];
  const float* b2m = (const float*)d_in[6];
  const float* W1p = (const float*)d_in[7];
  const float* b1p = (const float*)d_in[8];
  const float* W2p = (const float*)d_in[9];
  const float* b2p = (const float*)d_in[10];
  const float* mag_scale = (const float*)d_in[11];

  float* ws = (float*)d_ws;
  float* partR = ws;                       // NCHUNK*B*D = 1048576
  float* partI = ws + 1048576;             // 1048576
  float* cntP  = ws + 2097152;             // NCHUNK*B = 1024
  float* anR   = ws + 2098176;             // 16384
  float* anI   = ws + 2114560;             // 16384

  dim3 g(NCHUNK, BB);
  reduce_kernel<<<g, 256, 0, stream>>>(zr, zi, mask, partR, partI, cntP);

  mlp_kernel<<<BB * DD / 256, 256, 0, stream>>>(
      partR, partI, cntP, W1m, b1m, W2m, b2m, W1p, b1p, W2p, b2p, mag_scale, anR, anI);

  add_kernel<<<g, 256, 0, stream>>>(zr, zi, anR, anI, (float*)d_out);
}